// Round 1
// baseline (141.956 us; speedup 1.0000x reference)
//
#include <hip/hip_runtime.h>
#include <hip/hip_bf16.h>
#include <stdint.h>

// Problem constants
#define BB 32
#define NNODE 512
#define CC 16
#define DD 256
#define OO 256
#define K3 768          // 3*D
#define TM 32           // nodes per block
#define NSLAB 24        // K3/32
#define ASTR 776        // 768 + 8 pad (bf16 units) -> breaks 16-way LDS conflict
#define BSTR 40         // 32 + 8 pad  (bf16 units)

typedef __attribute__((ext_vector_type(8))) short bf16x8;
typedef __attribute__((ext_vector_type(4))) float f32x4;

__device__ __forceinline__ unsigned short f2bf(float x) {
    // RNE float->bf16 (inputs are finite gaussians; no NaN handling needed)
    unsigned u = __builtin_bit_cast(unsigned, x);
    u += 0x7FFFu + ((u >> 16) & 1u);
    return (unsigned short)(u >> 16);
}

__device__ __forceinline__ void st_bf4(unsigned short* p, float4 v) {
    uint2 u;
    u.x = (unsigned)f2bf(v.x) | ((unsigned)f2bf(v.y) << 16);
    u.y = (unsigned)f2bf(v.z) | ((unsigned)f2bf(v.w) << 16);
    *(uint2*)p = u;
}

// Pre-convert weights fp32 -> bf16, laid out K-slab-major for coalesced staging:
// wsb[slab][n][kw] with k = slab*32+kw, flat w row k: 0..255=w_t, 256..511=w_r, 512..767=w_l
__global__ void prep_w(const float* __restrict__ wt,
                       const float* __restrict__ wr,
                       const float* __restrict__ wl,
                       unsigned short* __restrict__ wsb) {
    int t = blockIdx.x * 256 + threadIdx.x;   // 0..196607
    int k = t >> 8;                           // 0..767
    int n = t & 255;
    const float* s = (k < 256) ? wt : ((k < 512) ? wr : wl);
    float v = s[(k & 255) * OO + n];
    wsb[(k >> 5) * (OO * 32) + n * 32 + (k & 31)] = f2bf(v);
}

__global__ __launch_bounds__(256, 2) void tbcnn_main(
    const float* __restrict__ nodes, const int* __restrict__ children,
    const unsigned short* __restrict__ wsb, const float* __restrict__ conv,
    float* __restrict__ out) {

    __shared__ unsigned short Atile[TM * ASTR];  // 49664 B
    __shared__ unsigned short Bs[OO * BSTR];     // 20480 B

    const int tid  = threadIdx.x;
    const int wave = tid >> 6;
    const int lane = tid & 63;
    const int base = blockIdx.x * TM;            // flattened node index base (b*512+n)
    const float4* gnodes4 = (const float4*)nodes;

    // ---------------- Phase 1: gather + coefficient reduction -> A tile (bf16) -----
    // wave w handles nodes m = w*8 .. w*8+7; lane covers 4 contiguous d via float4
#pragma unroll 1
    for (int i = 0; i < 8; ++i) {
        const int m  = wave * 8 + i;
        const int nf = base + m;                 // = b*512 + n
        const int brow = (nf >> 9) << 9;         // b*512
        const int* ch = children + (nf << 4);
        int cj[CC];
        int ns = 0;
#pragma unroll
        for (int j = 0; j < CC; ++j) { cj[j] = ch[j]; ns += (cj[j] != 0) ? 1 : 0; }
        const float inv_den = (ns > 1) ? 1.0f / (float)(ns - 1) : 0.0f;

        float4 pt = gnodes4[(size_t)nf * 64 + lane];   // parent embedding (c_t = 1)
        float4 ar = make_float4(0.f, 0.f, 0.f, 0.f);
        float4 al = make_float4(0.f, 0.f, 0.f, 0.f);
#pragma unroll
        for (int j = 0; j < CC; ++j) {
            if (cj[j] != 0) {
                // matches reference _coefs incl. the ns==1 "singles" path
                float crr = (ns == 1) ? ((j == 0) ? 0.5f : 0.0f) : (float)j * inv_den;
                float cll = 1.0f - crr;
                float4 e = gnodes4[((size_t)(brow + cj[j])) * 64 + lane];
                ar.x += crr * e.x; ar.y += crr * e.y; ar.z += crr * e.z; ar.w += crr * e.w;
                al.x += cll * e.x; al.y += cll * e.y; al.z += cll * e.z; al.w += cll * e.w;
            }
        }
        unsigned short* arow = &Atile[m * ASTR];
        st_bf4(arow + 0   + lane * 4, pt);   // k 0..255   : w_t part
        st_bf4(arow + 256 + lane * 4, ar);   // k 256..511 : w_r part
        st_bf4(arow + 512 + lane * 4, al);   // k 512..767 : w_l part
    }
    __syncthreads();

    // ---------------- Phase 2: MFMA GEMM (32 x 768) x (768 x 256) ------------------
    const int quad = lane >> 4;
    const int l16  = lane & 15;
    f32x4 acc[2][4];
#pragma unroll
    for (int mi = 0; mi < 2; ++mi)
#pragma unroll
        for (int ni = 0; ni < 4; ++ni)
            acc[mi][ni] = (f32x4){0.f, 0.f, 0.f, 0.f};

#pragma unroll 1
    for (int s = 0; s < NSLAB; ++s) {
        // stage B slab: 8192 bf16 contiguous in ws -> padded LDS [n][kw]
#pragma unroll
        for (int c4 = 0; c4 < 4; ++c4) {
            int e = (c4 * 256 + tid) * 8;            // element offset, 8 bf16 per 16B
            bf16x8 v = *(const bf16x8*)(wsb + s * 8192 + e);
            int nrow = e >> 5;
            int kw   = e & 31;
            *(bf16x8*)&Bs[nrow * BSTR + kw] = v;
        }
        __syncthreads();

        bf16x8 afr[2], bfr[4];
#pragma unroll
        for (int mi = 0; mi < 2; ++mi)
            afr[mi] = *(const bf16x8*)&Atile[(mi * 16 + l16) * ASTR + s * 32 + quad * 8];
#pragma unroll
        for (int ni = 0; ni < 4; ++ni)
            bfr[ni] = *(const bf16x8*)&Bs[(wave * 64 + ni * 16 + l16) * BSTR + quad * 8];
#pragma unroll
        for (int mi = 0; mi < 2; ++mi)
#pragma unroll
            for (int ni = 0; ni < 4; ++ni)
                acc[mi][ni] = __builtin_amdgcn_mfma_f32_16x16x32_bf16(
                    afr[mi], bfr[ni], acc[mi][ni], 0, 0, 0);
        __syncthreads();
    }

    // ---------------- Epilogue: + conv bias, leaky_relu(0.01), store fp32 ----------
#pragma unroll
    for (int ni = 0; ni < 4; ++ni) {
        const int o = wave * 64 + ni * 16 + l16;
        const float cv = conv[o];
#pragma unroll
        for (int mi = 0; mi < 2; ++mi) {
#pragma unroll
            for (int r = 0; r < 4; ++r) {
                const int mloc = mi * 16 + quad * 4 + r;   // C/D: row=quad*4+reg, col=l16
                float v = acc[mi][ni][r] + cv;
                v = (v > 0.f) ? v : 0.01f * v;
                out[(size_t)(base + mloc) * OO + o] = v;
            }
        }
    }
}

extern "C" void kernel_launch(void* const* d_in, const int* in_sizes, int n_in,
                              void* d_out, int out_size, void* d_ws, size_t ws_size,
                              hipStream_t stream) {
    // setup_inputs order: nodes, w_t, w_l, w_r, conv, children
    const float* nodes    = (const float*)d_in[0];
    const float* w_t      = (const float*)d_in[1];
    const float* w_l      = (const float*)d_in[2];
    const float* w_r      = (const float*)d_in[3];
    const float* conv     = (const float*)d_in[4];
    const int*   children = (const int*)d_in[5];

    unsigned short* wsb = (unsigned short*)d_ws;   // needs 768*256*2 = 393216 B

    // weights stacked as [w_t, w_r, w_l] to match einsum k-order
    prep_w<<<768, 256, 0, stream>>>(w_t, w_r, w_l, wsb);
    tbcnn_main<<<512, 256, 0, stream>>>(nodes, children, wsb, conv, (float*)d_out);
}

// Round 2
// 115.045 us; speedup vs baseline: 1.2339x; 1.2339x over previous
//
#include <hip/hip_runtime.h>
#include <hip/hip_bf16.h>
#include <stdint.h>

// Problem constants
#define BB 32
#define NNODE 512
#define CC 16
#define DD 256
#define OO 256
#define K3 768          // 3*D
#define TM 32           // nodes per block
#define NSLAB 24        // K3/32
#define ASTR 776        // 768 + 8 pad (bf16); row = 1552 B, 16B-aligned for b128

typedef __attribute__((ext_vector_type(8))) short bf16x8;
typedef __attribute__((ext_vector_type(4))) float f32x4;

__device__ __forceinline__ unsigned short f2bf(float x) {
    unsigned u = __builtin_bit_cast(unsigned, x);
    u += 0x7FFFu + ((u >> 16) & 1u);
    return (unsigned short)(u >> 16);
}

__device__ __forceinline__ void st_bf4(unsigned short* p, float4 v) {
    uint2 u;
    u.x = (unsigned)f2bf(v.x) | ((unsigned)f2bf(v.y) << 16);
    u.y = (unsigned)f2bf(v.z) | ((unsigned)f2bf(v.w) << 16);
    *(uint2*)p = u;
}

// Weights fp32 -> bf16, K-slab-major wsb[slab][n][kw] (k = slab*32+kw;
// k rows 0..255 = w_t, 256..511 = w_r, 512..767 = w_l).
// One block per slab; LDS transpose so both global read and write coalesce.
__global__ void prep_w(const float* __restrict__ wt,
                       const float* __restrict__ wr,
                       const float* __restrict__ wl,
                       unsigned short* __restrict__ wsb) {
    __shared__ unsigned short T[256 * 40];   // row pad 40 -> 80 B, 16B-aligned
    const int slab = blockIdx.x;             // 0..23
    const int n = threadIdx.x;               // 0..255
#pragma unroll
    for (int kk = 0; kk < 32; ++kk) {
        const int k = slab * 32 + kk;
        const float* s = (k < 256) ? wt : ((k < 512) ? wr : wl);
        T[n * 40 + kk] = f2bf(s[(k & 255) * OO + n]);   // coalesced fp32 read
    }
    __syncthreads();
    uint4* dst = (uint4*)(wsb + slab * 8192 + n * 32);  // 64 B contiguous/thread
    const uint4* src = (const uint4*)&T[n * 40];
#pragma unroll
    for (int q = 0; q < 4; ++q) dst[q] = src[q];
}

__global__ __launch_bounds__(512, 4) void tbcnn_main(
    const float* __restrict__ nodes, const int* __restrict__ children,
    const unsigned short* __restrict__ wsb, const float* __restrict__ conv,
    float* __restrict__ out) {

    __shared__ unsigned short Atile[TM * ASTR];  // 49,664 B

    const int tid  = threadIdx.x;
    const int wave = tid >> 6;
    const int lane = tid & 63;
    // XCD swizzle: dispatch is round-robin over 8 XCDs; map so each XCD owns
    // 4 whole batches (batch slice = 512 KB, 4 batches = 2 MB < 4 MB L2).
    const int p  = blockIdx.x;
    const int lb = (p & 7) * 64 + (p >> 3);
    const int base = lb * TM;                    // flattened b*512 + n
    const float4* gnodes4 = (const float4*)nodes;

    // ---------------- Phase 1: branchless gather + reduce -> A tile (bf16) ----
    // 8 waves x 4 nodes; all 17 loads per node unconditional & independent.
#pragma unroll 1
    for (int i = 0; i < 4; ++i) {
        const int m  = wave * 4 + i;
        const int nf = base + m;
        const int brow = (nf >> 9) << 9;         // b*512
        const int4* ch4 = (const int4*)(children + (nf << 4));
        int4 c0 = ch4[0], c1 = ch4[1], c2 = ch4[2], c3 = ch4[3];
        int cj[CC] = {c0.x, c0.y, c0.z, c0.w, c1.x, c1.y, c1.z, c1.w,
                      c2.x, c2.y, c2.z, c2.w, c3.x, c3.y, c3.z, c3.w};
        int ns = 0;
#pragma unroll
        for (int j = 0; j < CC; ++j) ns += (cj[j] != 0) ? 1 : 0;
        const float inv_den = (ns > 1) ? 1.0f / (float)(ns - 1) : 0.0f;
        const bool single = (ns == 1);

        float4 pt = gnodes4[(size_t)nf * 64 + lane];
        float4 ar = make_float4(0.f, 0.f, 0.f, 0.f);
        float4 al = make_float4(0.f, 0.f, 0.f, 0.f);
#pragma unroll
        for (int j = 0; j < CC; ++j) {
            const int idx = cj[j];
            const float hasf = (idx != 0) ? 1.0f : 0.0f;
            float4 e = gnodes4[((size_t)(brow + idx)) * 64 + lane];
            // reference _coefs, masked instead of branched:
            //  ns==1: c_r = 0.5 at slot 0 (emb masked by hasf); else j/(ns-1)
            const float crr_raw = single ? ((j == 0) ? 0.5f : 0.0f)
                                         : (float)j * inv_den * hasf;
            const float cr = crr_raw * hasf;
            const float cl = (1.0f - crr_raw) * hasf;
            ar.x += cr * e.x; ar.y += cr * e.y; ar.z += cr * e.z; ar.w += cr * e.w;
            al.x += cl * e.x; al.y += cl * e.y; al.z += cl * e.z; al.w += cl * e.w;
        }
        unsigned short* arow = &Atile[m * ASTR];
        st_bf4(arow + 0   + lane * 4, pt);   // k 0..255   : w_t
        st_bf4(arow + 256 + lane * 4, ar);   // k 256..511 : w_r
        st_bf4(arow + 512 + lane * 4, al);   // k 512..767 : w_l
    }
    __syncthreads();

    // ---------------- Phase 2: MFMA, B direct from global (L2) ---------------
    // wave -> (wr = row half, wc = col quarter): 16x64 output strip each.
    const int wr = wave >> 2;
    const int wc = wave & 3;
    const int quad = lane >> 4;
    const int l16  = lane & 15;
    f32x4 acc[4];
#pragma unroll
    for (int ni = 0; ni < 4; ++ni) acc[ni] = (f32x4){0.f, 0.f, 0.f, 0.f};

#pragma unroll 2
    for (int s = 0; s < NSLAB; ++s) {
        bf16x8 a = *(const bf16x8*)&Atile[(wr * 16 + l16) * ASTR + s * 32 + quad * 8];
#pragma unroll
        for (int ni = 0; ni < 4; ++ni) {
            bf16x8 b = *(const bf16x8*)(wsb + s * 8192
                                        + (wc * 64 + ni * 16 + l16) * 32 + quad * 8);
            acc[ni] = __builtin_amdgcn_mfma_f32_16x16x32_bf16(a, b, acc[ni], 0, 0, 0);
        }
    }

    // ---------------- Epilogue: + conv, leaky_relu(0.01), fp32 store ---------
#pragma unroll
    for (int ni = 0; ni < 4; ++ni) {
        const int o = wc * 64 + ni * 16 + l16;
        const float cv = conv[o];
#pragma unroll
        for (int r = 0; r < 4; ++r) {
            const int row = base + wr * 16 + quad * 4 + r;  // C/D: row=quad*4+reg
            float v = acc[ni][r] + cv;
            v = (v > 0.f) ? v : 0.01f * v;
            out[(size_t)row * OO + o] = v;
        }
    }
}

extern "C" void kernel_launch(void* const* d_in, const int* in_sizes, int n_in,
                              void* d_out, int out_size, void* d_ws, size_t ws_size,
                              hipStream_t stream) {
    // setup_inputs order: nodes, w_t, w_l, w_r, conv, children
    const float* nodes    = (const float*)d_in[0];
    const float* w_t      = (const float*)d_in[1];
    const float* w_l      = (const float*)d_in[2];
    const float* w_r      = (const float*)d_in[3];
    const float* conv     = (const float*)d_in[4];
    const int*   children = (const int*)d_in[5];

    unsigned short* wsb = (unsigned short*)d_ws;   // 768*256*2 = 393,216 B

    prep_w<<<24, 256, 0, stream>>>(w_t, w_r, w_l, wsb);
    tbcnn_main<<<512, 512, 0, stream>>>(nodes, children, wsb, conv, (float*)d_out);
}

// Round 3
// 106.984 us; speedup vs baseline: 1.3269x; 1.0753x over previous
//
#include <hip/hip_runtime.h>
#include <hip/hip_bf16.h>
#include <stdint.h>

// Problem: B=32, N=512, C=16, D=O=256.  Flattened nodes = 16384.
#define CC 16
#define OO 256
#define NSLAB 24            // K = 768 = 24 slabs of 32
#define MT_ROWS 64          // GEMM M-tile rows
#define SLAB_ELS (MT_ROWS * 32)          // 2048 bf16 per (mtile,slab) chunk
#define MT_ELS (NSLAB * SLAB_ELS)        // 49152 bf16 per mtile
#define AGG_ELS (16384 * 768)            // ws: agg is 25.2 MB
#define NGB 2048            // gather blocks (8 nodes each)

typedef __attribute__((ext_vector_type(8))) short bf16x8;
typedef __attribute__((ext_vector_type(4))) float f32x4;

__device__ __forceinline__ unsigned short f2bf(float x) {
    unsigned u = __builtin_bit_cast(unsigned, x);
    u += 0x7FFFu + ((u >> 16) & 1u);
    return (unsigned short)(u >> 16);
}

__device__ __forceinline__ void st_bf4(unsigned short* p, float4 v) {
    uint2 u;
    u.x = (unsigned)f2bf(v.x) | ((unsigned)f2bf(v.y) << 16);
    u.y = (unsigned)f2bf(v.z) | ((unsigned)f2bf(v.w) << 16);
    *(uint2*)p = u;
}

// async 16B global -> LDS (wave-uniform LDS base + lane*16)
__device__ __forceinline__ void cp16(const void* g, void* l) {
    __builtin_amdgcn_global_load_lds(
        (const __attribute__((address_space(1))) unsigned int*)g,
        (__attribute__((address_space(3))) unsigned int*)l, 16, 0, 0);
}

// ---------------------------------------------------------------------------
// Kernel 1: gather + coefficient reduce -> agg (bf16, GEMM-staging layout)
//           + 24 trailing blocks convert weights -> wsb[slab][n][kw]
// agg layout: [mtile][slab][row64][kw32]  (so GEMM stages with linear cp16)
// ---------------------------------------------------------------------------
__global__ __launch_bounds__(256, 4) void gather_prep(
    const float* __restrict__ nodes, const int* __restrict__ children,
    const float* __restrict__ wt, const float* __restrict__ wrp,
    const float* __restrict__ wl, unsigned short* __restrict__ agg,
    unsigned short* __restrict__ wsb) {

    __shared__ unsigned short T[256 * 40];   // used only by prep blocks (20 KB)
    const int p = blockIdx.x;
    const int tid = threadIdx.x;

    if (p >= NGB) {
        // ---- weight prep: one block per K-slab, LDS transpose ----
        const int slab = p - NGB;            // 0..23
        const int n = tid;                   // 0..255
#pragma unroll
        for (int kk = 0; kk < 32; ++kk) {
            const int k = slab * 32 + kk;    // 0..255 w_t, 256..511 w_r, 512..767 w_l
            const float* s = (k < 256) ? wt : ((k < 512) ? wrp : wl);
            T[n * 40 + kk] = f2bf(s[(k & 255) * OO + n]);
        }
        __syncthreads();
        uint4* dst = (uint4*)(wsb + slab * 8192 + n * 32);
        const uint4* src = (const uint4*)&T[n * 40];
#pragma unroll
        for (int q = 0; q < 4; ++q) dst[q] = src[q];
        return;
    }

    // ---- gather: XCD swizzle so each XCD owns 4 whole batches (L2-resident) --
    const int wave = tid >> 6;
    const int lane = tid & 63;
    const int lb = (p & 7) * 256 + (p >> 3);
    const int base = lb * 8;                 // 8 nodes per block, 2 per wave
    const float4* g4 = (const float4*)nodes;

#pragma unroll
    for (int i = 0; i < 2; ++i) {
        const int nf = base + wave * 2 + i;
        const int brow = nf & ~511;          // b*512
        const int4* ch4 = (const int4*)(children + (nf << 4));
        int4 c0 = ch4[0], c1 = ch4[1], c2 = ch4[2], c3 = ch4[3];
        int cj[CC] = {c0.x, c0.y, c0.z, c0.w, c1.x, c1.y, c1.z, c1.w,
                      c2.x, c2.y, c2.z, c2.w, c3.x, c3.y, c3.z, c3.w};
        int ns = 0;
#pragma unroll
        for (int j = 0; j < CC; ++j) ns += (cj[j] != 0) ? 1 : 0;
        const float inv_den = (ns > 1) ? 1.0f / (float)(ns - 1) : 0.0f;
        const bool single = (ns == 1);

        float4 pt = g4[(size_t)nf * 64 + lane];
        float4 ar = make_float4(0.f, 0.f, 0.f, 0.f);
        float4 al = make_float4(0.f, 0.f, 0.f, 0.f);
#pragma unroll
        for (int j = 0; j < CC; ++j) {
            const int idx = cj[j];
            const float hasf = (idx != 0) ? 1.0f : 0.0f;
            float4 e = g4[((size_t)(brow + idx)) * 64 + lane];
            const float crr_raw = single ? ((j == 0) ? 0.5f : 0.0f)
                                         : (float)j * inv_den;
            const float cr = crr_raw * hasf;
            const float cl = (1.0f - crr_raw) * hasf;
            ar.x += cr * e.x; ar.y += cr * e.y; ar.z += cr * e.z; ar.w += cr * e.w;
            al.x += cl * e.x; al.y += cl * e.y; al.z += cl * e.z; al.w += cl * e.w;
        }
        // store into agg[mtile][slab][row][kw]; lane covers k = part*256 + lane*4
        const int sl = lane >> 3;            // slab-within-part
        const int kw = (lane & 7) * 4;
        unsigned short* rowp = agg + (size_t)(nf >> 6) * MT_ELS
                                   + (size_t)(nf & 63) * 32 + kw;
        st_bf4(rowp + (size_t)(0  + sl) * SLAB_ELS, pt);   // k 0..255   : w_t
        st_bf4(rowp + (size_t)(8  + sl) * SLAB_ELS, ar);   // k 256..511 : w_r
        st_bf4(rowp + (size_t)(16 + sl) * SLAB_ELS, al);   // k 512..767 : w_l
    }
}

// ---------------------------------------------------------------------------
// Kernel 2: GEMM (16384 x 768) x (768 x 256) + bias + leaky_relu -> out fp32
// 64x128 tile, 512 blocks (2/CU), dbuf LDS, global_load_lds staging.
// ---------------------------------------------------------------------------
__global__ __launch_bounds__(256, 2) void gemm_ep(
    const unsigned short* __restrict__ agg, const unsigned short* __restrict__ wsb,
    const float* __restrict__ conv, float* __restrict__ out) {

    __shared__ unsigned short Ab[2][SLAB_ELS];   // 2 x 4 KB  (64 rows x 32 k)
    __shared__ unsigned short Bb[2][4096];       // 2 x 8 KB  (128 cols x 32 k)

    const int tid  = threadIdx.x;
    const int wave = tid >> 6;
    const int lane = tid & 63;
    const int quad = lane >> 4;
    const int l16  = lane & 15;
    const int mtile = blockIdx.x >> 1;           // 0..255
    const int ntile = blockIdx.x & 1;            // 0..1
    const int wrr = wave >> 1;                   // M half (32 rows)
    const int wcc = wave & 1;                    // N half (64 cols)

    const char* aggb = (const char*)agg + (size_t)mtile * (MT_ELS * 2);
    const char* wsbb = (const char*)wsb + ntile * 8192;
    const int toff  = tid * 16;
    const int wbase = (tid & ~63) * 16;          // wave-uniform LDS offset

    f32x4 acc[2][4];
#pragma unroll
    for (int mi = 0; mi < 2; ++mi)
#pragma unroll
        for (int ni = 0; ni < 4; ++ni)
            acc[mi][ni] = (f32x4){0.f, 0.f, 0.f, 0.f};

    auto stage = [&](int s, int b) {
        const char* ga = aggb + s * 4096 + toff;           // 4 KB A chunk
        cp16(ga, (char*)&Ab[b][0] + wbase);
        const char* gb = wsbb + s * 16384 + toff;          // 8 KB B chunk
        cp16(gb,        (char*)&Bb[b][0] + wbase);
        cp16(gb + 4096, (char*)&Bb[b][0] + wbase + 4096);
    };

    stage(0, 0);
#pragma unroll 1
    for (int s = 0; s < NSLAB; ++s) {
        const int cur = s & 1;
        __syncthreads();                  // staging of slab s complete (vmcnt drain)
        if (s + 1 < NSLAB) stage(s + 1, cur ^ 1);   // async prefetch, other buffer

        bf16x8 af[2], bfr[4];
#pragma unroll
        for (int mi = 0; mi < 2; ++mi)
            af[mi] = *(const bf16x8*)&Ab[cur][(wrr * 32 + mi * 16 + l16) * 32 + quad * 8];
#pragma unroll
        for (int ni = 0; ni < 4; ++ni)
            bfr[ni] = *(const bf16x8*)&Bb[cur][(wcc * 64 + ni * 16 + l16) * 32 + quad * 8];
#pragma unroll
        for (int mi = 0; mi < 2; ++mi)
#pragma unroll
            for (int ni = 0; ni < 4; ++ni)
                acc[mi][ni] = __builtin_amdgcn_mfma_f32_16x16x32_bf16(
                    af[mi], bfr[ni], acc[mi][ni], 0, 0, 0);
    }

    // epilogue: + conv, leaky_relu(0.01), fp32 store
#pragma unroll
    for (int ni = 0; ni < 4; ++ni) {
        const int col = ntile * 128 + wcc * 64 + ni * 16 + l16;
        const float cv = conv[col];
#pragma unroll
        for (int mi = 0; mi < 2; ++mi) {
#pragma unroll
            for (int r = 0; r < 4; ++r) {
                const int row = mtile * 64 + wrr * 32 + mi * 16 + quad * 4 + r;
                float v = acc[mi][ni][r] + cv;
                v = (v > 0.f) ? v : 0.01f * v;
                out[(size_t)row * OO + col] = v;
            }
        }
    }
}

extern "C" void kernel_launch(void* const* d_in, const int* in_sizes, int n_in,
                              void* d_out, int out_size, void* d_ws, size_t ws_size,
                              hipStream_t stream) {
    // setup_inputs order: nodes, w_t, w_l, w_r, conv, children
    const float* nodes    = (const float*)d_in[0];
    const float* w_t      = (const float*)d_in[1];
    const float* w_l      = (const float*)d_in[2];
    const float* w_r      = (const float*)d_in[3];
    const float* conv     = (const float*)d_in[4];
    const int*   children = (const int*)d_in[5];

    unsigned short* agg = (unsigned short*)d_ws;          // 25,165,824 B
    unsigned short* wsb = agg + AGG_ELS;                  // + 393,216 B

    gather_prep<<<NGB + 24, 256, 0, stream>>>(nodes, children, w_t, w_r, w_l,
                                              agg, wsb);
    gemm_ep<<<512, 256, 0, stream>>>(agg, wsb, conv, (float*)d_out);
}

// Round 4
// 105.654 us; speedup vs baseline: 1.3436x; 1.0126x over previous
//
#include <hip/hip_runtime.h>
#include <hip/hip_bf16.h>
#include <stdint.h>

// Problem: B=32, N=512, C=16, D=O=256.  Flattened nodes = 16384.
#define CC 16
#define OO 256
#define NSLAB 24            // K = 768 = 24 slabs of 32
#define MT_ROWS 64          // GEMM M-tile rows
#define SLAB_ELS (MT_ROWS * 32)          // 2048 bf16 per (mtile,slab) chunk
#define MT_ELS (NSLAB * SLAB_ELS)        // 49152 bf16 per mtile
#define AGG_ELS (16384 * 768)            // ws: agg is 25.2 MB
#define NGB 2048            // gather blocks (8 nodes each)

typedef __attribute__((ext_vector_type(8))) short bf16x8;
typedef __attribute__((ext_vector_type(4))) float f32x4;

__device__ __forceinline__ unsigned short f2bf(float x) {
    unsigned u = __builtin_bit_cast(unsigned, x);
    u += 0x7FFFu + ((u >> 16) & 1u);
    return (unsigned short)(u >> 16);
}

__device__ __forceinline__ void st_bf4(unsigned short* p, float4 v) {
    uint2 u;
    u.x = (unsigned)f2bf(v.x) | ((unsigned)f2bf(v.y) << 16);
    u.y = (unsigned)f2bf(v.z) | ((unsigned)f2bf(v.w) << 16);
    *(uint2*)p = u;
}

// async 16B global -> LDS (wave-uniform LDS base + lane*16)
__device__ __forceinline__ void cp16(const void* g, void* l) {
    __builtin_amdgcn_global_load_lds(
        (const __attribute__((address_space(1))) unsigned int*)g,
        (__attribute__((address_space(3))) unsigned int*)l, 16, 0, 0);
}

// ---------------------------------------------------------------------------
// Kernel 1: gather + coefficient reduce -> agg (bf16, GEMM-staging layout)
//           + 24 trailing blocks convert weights -> wsb[slab][n][kw]
// agg layout: [mtile][slab][row64][kw32]  (so GEMM stages with linear cp16)
// Latency fix: children scalarized (readfirstlane -> s_load); all 17 float4
// gathers issued into a register batch BEFORE any reduction consumes them.
// ---------------------------------------------------------------------------
__global__ __launch_bounds__(256, 4) void gather_prep(
    const float* __restrict__ nodes, const int* __restrict__ children,
    const float* __restrict__ wt, const float* __restrict__ wrp,
    const float* __restrict__ wl, unsigned short* __restrict__ agg,
    unsigned short* __restrict__ wsb) {

    __shared__ unsigned short T[256 * 40];   // used only by prep blocks (20 KB)
    const int p = blockIdx.x;
    const int tid = threadIdx.x;

    if (p >= NGB) {
        // ---- weight prep: one block per K-slab, LDS transpose ----
        const int slab = p - NGB;            // 0..23
        const int n = tid;                   // 0..255
#pragma unroll
        for (int kk = 0; kk < 32; ++kk) {
            const int k = slab * 32 + kk;    // 0..255 w_t, 256..511 w_r, 512..767 w_l
            const float* s = (k < 256) ? wt : ((k < 512) ? wrp : wl);
            T[n * 40 + kk] = f2bf(s[(k & 255) * OO + n]);
        }
        __syncthreads();
        uint4* dst = (uint4*)(wsb + slab * 8192 + n * 32);
        const uint4* src = (const uint4*)&T[n * 40];
#pragma unroll
        for (int q = 0; q < 4; ++q) dst[q] = src[q];
        return;
    }

    // ---- gather: XCD swizzle so each XCD owns 4 whole batches (L2-resident) --
    const int wave = tid >> 6;
    const int lane = tid & 63;
    const int lb = (p & 7) * 256 + (p >> 3);
    const int base = lb * 8;                 // 8 nodes per block, 2 per wave
    const float4* g4 = (const float4*)nodes;

#pragma unroll 1
    for (int i = 0; i < 2; ++i) {
        // nf is wave-uniform by construction; make it provably so -> s_load path
        const int nf = __builtin_amdgcn_readfirstlane(base + wave * 2 + i);
        const int brow = nf & ~511;          // b*512
        const int* chp = children + (nf << 4);
        int cj[CC];
#pragma unroll
        for (int j = 0; j < CC; ++j) cj[j] = chp[j];   // scalar loads (SGPR)
        int ns = 0;
#pragma unroll
        for (int j = 0; j < CC; ++j) ns += (cj[j] != 0) ? 1 : 0;
        const float inv_den = (ns > 1) ? 1.0f / (float)(ns - 1) : 0.0f;
        const bool single = (ns == 1);

        // ---- issue ALL gathers first (17 loads in flight) ----
        float4 pt = g4[(size_t)nf * 64 + lane];
        float4 e[CC];
#pragma unroll
        for (int j = 0; j < CC; ++j)
            e[j] = g4[(size_t)(brow + cj[j]) * 64 + lane];

        // ---- reduce with reference _coefs (branchless mask) ----
        float4 ar = make_float4(0.f, 0.f, 0.f, 0.f);
        float4 al = make_float4(0.f, 0.f, 0.f, 0.f);
#pragma unroll
        for (int j = 0; j < CC; ++j) {
            const float hasf = (cj[j] != 0) ? 1.0f : 0.0f;
            const float crr_raw = single ? ((j == 0) ? 0.5f : 0.0f)
                                         : (float)j * inv_den;
            const float cr = crr_raw * hasf;
            const float cl = (1.0f - crr_raw) * hasf;
            ar.x += cr * e[j].x; ar.y += cr * e[j].y;
            ar.z += cr * e[j].z; ar.w += cr * e[j].w;
            al.x += cl * e[j].x; al.y += cl * e[j].y;
            al.z += cl * e[j].z; al.w += cl * e[j].w;
        }
        // store into agg[mtile][slab][row][kw]; lane covers k = part*256 + lane*4
        const int sl = lane >> 3;            // slab-within-part
        const int kw = (lane & 7) * 4;
        unsigned short* rowp = agg + (size_t)(nf >> 6) * MT_ELS
                                   + (size_t)(nf & 63) * 32 + kw;
        st_bf4(rowp + (size_t)(0  + sl) * SLAB_ELS, pt);   // k 0..255   : w_t
        st_bf4(rowp + (size_t)(8  + sl) * SLAB_ELS, ar);   // k 256..511 : w_r
        st_bf4(rowp + (size_t)(16 + sl) * SLAB_ELS, al);   // k 512..767 : w_l
    }
}

// ---------------------------------------------------------------------------
// Kernel 2: GEMM (16384 x 768) x (768 x 256) + bias + leaky_relu -> out fp32
// 64x128 tile, 512 blocks (2/CU), dbuf LDS, global_load_lds staging.
// ---------------------------------------------------------------------------
__global__ __launch_bounds__(256, 2) void gemm_ep(
    const unsigned short* __restrict__ agg, const unsigned short* __restrict__ wsb,
    const float* __restrict__ conv, float* __restrict__ out) {

    __shared__ unsigned short Ab[2][SLAB_ELS];   // 2 x 4 KB  (64 rows x 32 k)
    __shared__ unsigned short Bb[2][4096];       // 2 x 8 KB  (128 cols x 32 k)

    const int tid  = threadIdx.x;
    const int wave = tid >> 6;
    const int lane = tid & 63;
    const int quad = lane >> 4;
    const int l16  = lane & 15;
    const int mtile = blockIdx.x >> 1;           // 0..255
    const int ntile = blockIdx.x & 1;            // 0..1
    const int wrr = wave >> 1;                   // M half (32 rows)
    const int wcc = wave & 1;                    // N half (64 cols)

    const char* aggb = (const char*)agg + (size_t)mtile * (MT_ELS * 2);
    const char* wsbb = (const char*)wsb + ntile * 8192;
    const int toff  = tid * 16;
    const int wbase = (tid & ~63) * 16;          // wave-uniform LDS offset

    f32x4 acc[2][4];
#pragma unroll
    for (int mi = 0; mi < 2; ++mi)
#pragma unroll
        for (int ni = 0; ni < 4; ++ni)
            acc[mi][ni] = (f32x4){0.f, 0.f, 0.f, 0.f};

    auto stage = [&](int s, int b) {
        const char* ga = aggb + s * 4096 + toff;           // 4 KB A chunk
        cp16(ga, (char*)&Ab[b][0] + wbase);
        const char* gb = wsbb + s * 16384 + toff;          // 8 KB B chunk
        cp16(gb,        (char*)&Bb[b][0] + wbase);
        cp16(gb + 4096, (char*)&Bb[b][0] + wbase + 4096);
    };

    stage(0, 0);
#pragma unroll 1
    for (int s = 0; s < NSLAB; ++s) {
        const int cur = s & 1;
        __syncthreads();                  // staging of slab s complete (vmcnt drain)
        if (s + 1 < NSLAB) stage(s + 1, cur ^ 1);   // async prefetch, other buffer

        bf16x8 af[2], bfr[4];
#pragma unroll
        for (int mi = 0; mi < 2; ++mi)
            af[mi] = *(const bf16x8*)&Ab[cur][(wrr * 32 + mi * 16 + l16) * 32 + quad * 8];
#pragma unroll
        for (int ni = 0; ni < 4; ++ni)
            bfr[ni] = *(const bf16x8*)&Bb[cur][(wcc * 64 + ni * 16 + l16) * 32 + quad * 8];
#pragma unroll
        for (int mi = 0; mi < 2; ++mi)
#pragma unroll
            for (int ni = 0; ni < 4; ++ni)
                acc[mi][ni] = __builtin_amdgcn_mfma_f32_16x16x32_bf16(
                    af[mi], bfr[ni], acc[mi][ni], 0, 0, 0);
    }

    // epilogue: + conv, leaky_relu(0.01), fp32 store
#pragma unroll
    for (int ni = 0; ni < 4; ++ni) {
        const int col = ntile * 128 + wcc * 64 + ni * 16 + l16;
        const float cv = conv[col];
#pragma unroll
        for (int mi = 0; mi < 2; ++mi) {
#pragma unroll
            for (int r = 0; r < 4; ++r) {
                const int row = mtile * 64 + wrr * 32 + mi * 16 + quad * 4 + r;
                float v = acc[mi][ni][r] + cv;
                v = (v > 0.f) ? v : 0.01f * v;
                out[(size_t)row * OO + col] = v;
            }
        }
    }
}

extern "C" void kernel_launch(void* const* d_in, const int* in_sizes, int n_in,
                              void* d_out, int out_size, void* d_ws, size_t ws_size,
                              hipStream_t stream) {
    // setup_inputs order: nodes, w_t, w_l, w_r, conv, children
    const float* nodes    = (const float*)d_in[0];
    const float* w_t      = (const float*)d_in[1];
    const float* w_l      = (const float*)d_in[2];
    const float* w_r      = (const float*)d_in[3];
    const float* conv     = (const float*)d_in[4];
    const int*   children = (const int*)d_in[5];

    unsigned short* agg = (unsigned short*)d_ws;          // 25,165,824 B
    unsigned short* wsb = agg + AGG_ELS;                  // + 393,216 B

    gather_prep<<<NGB + 24, 256, 0, stream>>>(nodes, children, w_t, w_r, w_l,
                                              agg, wsb);
    gemm_ep<<<512, 256, 0, stream>>>(agg, wsb, conv, (float*)d_out);
}